// Round 8
// baseline (333.815 us; speedup 1.0000x reference)
//
#include <hip/hip_runtime.h>
#include <cstdint>
#include <cstddef>

// LIF recurrent SNN, sinabs ThresholdSubtract.
//   B=32 independent batch rows -> 1 block per batch row.
//   Spikes ~4.4 sigma -> speculate "no spike in chunk", exact replay on hit.
// Round-8: PRODUCER/CONSUMER WAVE SPECIALIZATION (TLP, not ILP).
//   R1-R7 ledger: every single-wave software-pipeline (C arrays, inline-asm
//   loads, LDS-DMA same-wave, plain SSA loads, sched_barrier(0)) ended at
//   VGPR~70 and ~3400cy/chunk -- the RP-minimizing scheduler sinks x's
//   noalias/readonly loads to their use, exposing one serialized latency
//   chain per chunk. Structural fix: prefetch lives in DEDICATED WAVES whose
//   vmcnt stalls overlap the compute waves' work.
//   Block = 512 thr (8 waves): waves 0-3 consume (LIF math, LDS reads only),
//   waves 4-7 produce (global_load_lds DMA into a depth-3 LDS ring; each
//   wave owns 2 step-rows = 8 DMAs/chunk). Iteration i: producers issue
//   chunk i+2 then vmcnt(8) (drains chunk i+1, issued one iteration earlier
//   -> ~free); consumers process chunk i; one shared lgkm-only barrier.
//   Replay (rare) reads the resident ring slot; producers mirror replay's 8
//   barriers so s_barrier counts stay aligned across waves.
#define B_       32
#define T_       1000
#define N_       1024
#define THREADS_ 512           // 8 waves: 0-3 consumers, 4-7 producers
#define CWAVES_  4
#define CHUNK_   8
#define NCHUNK_  125
#define RING_    3
#define ZBLOCKS_ 1024

typedef float v4f __attribute__((ext_vector_type(4)));

// Barrier draining only LDS (lgkmcnt), NOT vmcnt: producer DMAs for future
// chunks stay in flight across the per-chunk barrier.
__device__ __forceinline__ void barrier_lds() {
  __asm__ volatile("s_waitcnt lgkmcnt(0)\n\ts_barrier" ::: "memory");
}

// Producer-only: wait until <= N of this wave's vmem ops outstanding.
#define VMWAIT(N) __asm__ volatile("s_waitcnt vmcnt(" #N ")" ::: "memory")

typedef const __attribute__((address_space(1))) void* gas_ptr;
typedef __attribute__((address_space(3))) void*       las_ptr;

__device__ __forceinline__ v4f vmax4(v4f a, v4f b) {
  v4f r;
  r.x = fmaxf(a.x, b.x); r.y = fmaxf(a.y, b.y);
  r.z = fmaxf(a.z, b.z); r.w = fmaxf(a.w, b.w);
  return r;
}

__global__ __launch_bounds__(THREADS_, 1)
void lif_fused(const float* __restrict__ x, const float* __restrict__ w,
               const float* __restrict__ brec_g, float* __restrict__ out,
               unsigned long long* __restrict__ ws_rec,
               unsigned int* __restrict__ ws_cnt, int cap)
{
  // ---------------- zero path: blocks >= 32 clear the output ----------------
  if (blockIdx.x >= B_) {
    const size_t n4 = (size_t)B_ * T_ * N_ / 4;
    size_t i = (size_t)(blockIdx.x - B_) * THREADS_ + threadIdx.x;
    const size_t stride = (size_t)(gridDim.x - B_) * THREADS_;
    v4f* o4 = (v4f*)out;
    v4f z = (v4f)(0.f);
    for (; i < n4; i += stride) __builtin_nontemporal_store(z, &o4[i]);
    return;
  }

  // ---------------- lif path: blocks 0..31, one batch row each --------------
  const int b    = blockIdx.x;
  const int tid  = threadIdx.x;
  const int lane = tid & 63;
  const int wv   = tid >> 6;            // 0..7
  const bool is_prod = (wv >= CWAVES_);
  const int pw   = wv - CWAVES_;        // producer wave id 0..3
  const int n0   = tid << 2;            // consumer: 4 owned neurons (wv<4 only)

  // depth-3 ring of x chunks (96KB) + exchange buffers (~8.5KB)
  __shared__ float xring[RING_][CHUNK_][N_];
  __shared__ unsigned long long s_cmask[2][CWAVES_];
  __shared__ unsigned long long s_mask [2][CWAVES_];
  __shared__ v4f                s_val  [2][256];
  __shared__ unsigned int       s_spkcnt;

  const float* xb = x + (size_t)b * (T_ * N_);

  // Producer wave pw DMAs step-rows 2pw, 2pw+1 of chunk cc into its ring slot.
  // lds dest = wave-uniform base + lane*16 (HW rule); src lane stride 16B.
  auto issue_chunk = [&](int cc) {
    const int slot = cc % RING_;
    const float* src = xb + (size_t)cc * (CHUNK_ * N_) + (lane << 2);
#pragma unroll
    for (int rr = 0; rr < 2; ++rr) {
      const int row = (pw << 1) + rr;
      const float* rs = src + row * N_;
      float* ld = &xring[slot][row][0];
#pragma unroll
      for (int q = 0; q < 4; ++q)
        __builtin_amdgcn_global_load_lds((gas_ptr)(rs + q * 256),
                                         (las_ptr)(ld + q * 256), 16, 0, 0);
    }
  };

  v4f state = (v4f)(0.f);
  v4f rec   = (v4f)(0.f);               // initial carry rec = 0 (NOT b_rec)
  v4f brec  = (v4f)(0.f);
  if (!is_prod) brec = *(const v4f*)(brec_g + n0);  // guarded: n0<1024 only for consumers

  // Exact replay of chunk i (rare): x read from the resident ring slot (LDS).
  auto replay = [&](int i) {
    v4f st = state;
    v4f r  = rec;
    const float* xr = &xring[i % RING_][0][0];
#pragma unroll 1
    for (int k = 0; k < CHUNK_; ++k) {
      const int q = k & 1;
      v4f xv = *(const v4f*)(xr + (size_t)k * N_ + n0);
      float tx = xv.x + r.x, ty = xv.y + r.y, tz = xv.z + r.z, tw = xv.w + r.w;
      float ax = (st.x > 0.f) ? floorf(st.x) : 0.f;
      float ay = (st.y > 0.f) ? floorf(st.y) : 0.f;
      float az = (st.z > 0.f) ? floorf(st.z) : 0.f;
      float aw = (st.w > 0.f) ? floorf(st.w) : 0.f;
      int ms = (ax != 0.f) | (ay != 0.f) | (az != 0.f) | (aw != 0.f);
      if (ms) {
        v4f v; v.x = ax; v.y = ay; v.z = az; v.w = aw;
        s_val[q][tid] = v;
        unsigned int off = (unsigned int)((i * CHUNK_ + k) * N_ + n0);
        float av[4] = {ax, ay, az, aw};
#pragma unroll
        for (int e = 0; e < 4; ++e) {
          if (av[e] != 0.f) {
            unsigned int idx = atomicAdd(&s_spkcnt, 1u);
            if ((int)idx < cap)
              ws_rec[(size_t)b * cap + idx] =
                  ((unsigned long long)(off + e) << 32) |
                  (unsigned long long)__float_as_uint(av[e]);
          }
        }
      }
      unsigned long long sm = __ballot(ms);
      if (lane == 0) s_mask[q][wv] = sm;
      st.x = (st.x - ax) * 0.9f + 0.1f * tx;
      st.y = (st.y - ay) * 0.9f + 0.1f * ty;
      st.z = (st.z - az) * 0.9f + 0.1f * tz;
      st.w = (st.w - aw) * 0.9f + 0.1f * tw;
      barrier_lds();
      // sparse rank-1 rec update: rec[n] = b_rec[n] + sum_j act[j]*w[n][j]
      v4f racc = brec;
#pragma unroll 1
      for (int w2 = 0; w2 < CWAVES_; ++w2) {
        unsigned long long mm = s_mask[q][w2];
        while (mm) {
          int l = __builtin_ctzll(mm);
          mm &= mm - 1;
          int j = (w2 << 6) + l;
          v4f v = s_val[q][j];
          int jn = j << 2;
          if (v.x != 0.f) {
            racc.x += v.x * w[(size_t)(n0 + 0) * N_ + jn];
            racc.y += v.x * w[(size_t)(n0 + 1) * N_ + jn];
            racc.z += v.x * w[(size_t)(n0 + 2) * N_ + jn];
            racc.w += v.x * w[(size_t)(n0 + 3) * N_ + jn];
          }
          if (v.y != 0.f) {
            int j1 = jn + 1;
            racc.x += v.y * w[(size_t)(n0 + 0) * N_ + j1];
            racc.y += v.y * w[(size_t)(n0 + 1) * N_ + j1];
            racc.z += v.y * w[(size_t)(n0 + 2) * N_ + j1];
            racc.w += v.y * w[(size_t)(n0 + 3) * N_ + j1];
          }
          if (v.z != 0.f) {
            int j2 = jn + 2;
            racc.x += v.z * w[(size_t)(n0 + 0) * N_ + j2];
            racc.y += v.z * w[(size_t)(n0 + 1) * N_ + j2];
            racc.z += v.z * w[(size_t)(n0 + 2) * N_ + j2];
            racc.w += v.z * w[(size_t)(n0 + 3) * N_ + j2];
          }
          if (v.w != 0.f) {
            int j3 = jn + 3;
            racc.x += v.w * w[(size_t)(n0 + 0) * N_ + j3];
            racc.y += v.w * w[(size_t)(n0 + 1) * N_ + j3];
            racc.z += v.w * w[(size_t)(n0 + 2) * N_ + j3];
            racc.w += v.w * w[(size_t)(n0 + 3) * N_ + j3];
          }
        }
      }
      r = racc;
    }
    state = st;
    rec   = r;
  };

  // ---- prologue: producers stage chunks 0,1; chunk 0 drained pre-barrier ----
  if (tid == 0) s_spkcnt = 0;
  if (is_prod) {
    issue_chunk(0);
    issue_chunk(1);
    VMWAIT(8);                   // chunk 0 landed (chunk 1 still in flight)
  }
  barrier_lds();

  // ---- main loop: 1 chunk per iteration, 1 shared barrier per chunk ----
#pragma unroll 1
  for (int i = 0; i < NCHUNK_; ++i) {
    v4f st, cmax;                // consumer-only values (garbage in producers)
    if (is_prod) {
      if (i + 2 < NCHUNK_) {
        issue_chunk(i + 2);      // newest 8 DMAs
        VMWAIT(8);               // drain chunk i+1 (issued last iter -> ~free)
      } else {
        VMWAIT(0);               // tail: drain whatever remains
      }
    } else {
      // speculative no-spike pass on chunk i from LDS.
      // Spike at step k iff pre-update state >= 1.0 -> track running max.
      // (st-0)*0.9+0.1*t is bit-identical to replay arithmetic with act==0.
      const float* xr = &xring[i % RING_][0][0];
      v4f x0 = *(const v4f*)(xr + 0 * N_ + n0);
      v4f x1 = *(const v4f*)(xr + 1 * N_ + n0);
      v4f x2 = *(const v4f*)(xr + 2 * N_ + n0);
      v4f x3 = *(const v4f*)(xr + 3 * N_ + n0);
      v4f x4 = *(const v4f*)(xr + 4 * N_ + n0);
      v4f x5 = *(const v4f*)(xr + 5 * N_ + n0);
      v4f x6 = *(const v4f*)(xr + 6 * N_ + n0);
      v4f x7 = *(const v4f*)(xr + 7 * N_ + n0);
      st = state;
      v4f rr = rec;              // incoming rec (brec unless prev chunk spiked)
      cmax = state;
#define SPEC_STEP(xf)                                                        \
      do {                                                                   \
        cmax = vmax4(cmax, st);                                              \
        v4f _t = (xf) + rr;                                                  \
        st = st * 0.9f + 0.1f * _t;                                          \
        rr = brec;                                                           \
      } while (0)
      SPEC_STEP(x0); SPEC_STEP(x1); SPEC_STEP(x2); SPEC_STEP(x3);
      SPEC_STEP(x4); SPEC_STEP(x5); SPEC_STEP(x6); SPEC_STEP(x7);
#undef SPEC_STEP
      float m = fmaxf(fmaxf(cmax.x, cmax.y), fmaxf(cmax.z, cmax.w));
      int any = (m >= 1.0f);
      unsigned long long wm = __ballot(any);
      if (lane == 0) s_cmask[i & 1][wv] = wm;
    }

    barrier_lds();               // lgkm-only: producer DMAs stay in flight

    unsigned long long anyblk =
        s_cmask[i & 1][0] | s_cmask[i & 1][1] |
        s_cmask[i & 1][2] | s_cmask[i & 1][3];

    if (anyblk == 0ULL) {
      if (!is_prod) { state = st; rec = brec; }  // fast path: output stays zero
    } else {
      if (!is_prod) {
        replay(i);               // 8 per-step barriers inside
      } else {
#pragma unroll 1
        for (int k = 0; k < CHUNK_; ++k) barrier_lds();  // mirror replay's
      }
    }
  }

  __syncthreads();                     // all replay appends done
  if (tid == 0) ws_cnt[b] = s_spkcnt;  // written unconditionally (ws poisoned)
}

// Apply the (few hundred) recorded spikes onto the zeroed output.
__global__ void scatter_spikes(const unsigned long long* __restrict__ rec,
                               const unsigned int* __restrict__ cnt,
                               float* __restrict__ out, int cap)
{
  int b = blockIdx.x;
  unsigned int n = cnt[b];
  if ((int)n > cap) n = cap;
  for (unsigned int i = threadIdx.x; i < n; i += blockDim.x) {
    unsigned long long r = rec[(size_t)b * cap + i];
    unsigned int off = (unsigned int)(r >> 32);
    float v = __uint_as_float((unsigned int)r);
    out[(size_t)b * (T_ * N_) + off] = v;
  }
}

extern "C" void kernel_launch(void* const* d_in, const int* in_sizes, int n_in,
                              void* d_out, int out_size, void* d_ws, size_t ws_size,
                              hipStream_t stream) {
  const float* x  = (const float*)d_in[0]; // [B,T,N] input_current
  const float* w  = (const float*)d_in[1]; // [N,N] w_rec (row-major [out,in])
  const float* br = (const float*)d_in[2]; // [N] b_rec
  float* out = (float*)d_out;              // [B,T,N] spikes

  // spike-record workspace layout: [32][cap] u64 records, then [32] u32 counts
  int cap = 4096;
  size_t need = (size_t)B_ * cap * 8 + B_ * 4;
  if (ws_size < need && ws_size > 256)
    cap = (int)((ws_size - 256) / ((size_t)B_ * 8));
  unsigned long long* rec = (unsigned long long*)d_ws;
  unsigned int* cnt = (unsigned int*)((char*)d_ws + (size_t)B_ * cap * 8);

  // blocks 0..31: LIF scan (4 compute + 4 producer waves per block);
  // blocks 32..: zero the output concurrently on the remaining CUs.
  lif_fused<<<B_ + ZBLOCKS_, THREADS_, 0, stream>>>(x, w, br, out, rec, cnt, cap);
  scatter_spikes<<<B_, THREADS_, 0, stream>>>(rec, cnt, out, cap);
}